// Round 8
// baseline (33798.257 us; speedup 1.0000x reference)
//
#include <hip/hip_runtime.h>

#define NT 2048
#define NI 128
#define NH 256
#define BPG 8
#define ZROW 640  // [x(128) | h0(256) | h1(256)]

typedef unsigned long long u64;

__device__ __forceinline__ float sigm(float v) {
  return 1.0f / (1.0f + __expf(-v));
}
__device__ __forceinline__ float tanh_fast(float v) {
  v = fminf(fmaxf(v, -15.0f), 15.0f);
  float e = __expf(-2.0f * v);
  return (1.0f - e) / (1.0f + e);
}
__device__ __forceinline__ float lstm_act(float gi, float gf, float gg, float go,
                                          float& c) {
  const float ii = sigm(gi), ff = sigm(gf), gt = tanh_fast(gg), oo = sigm(go);
  c = ff * c + ii * gt;
  return oo * tanh_fast(c);
}

// relaxed agent-scope: cross-XCD coherent, no cache-maintenance ops
__device__ __forceinline__ int ld_flag(const int* p) {
  return __hip_atomic_load(p, __ATOMIC_RELAXED, __HIP_MEMORY_SCOPE_AGENT);
}
__device__ __forceinline__ void st_flag(int* p, int v) {
  __hip_atomic_store(p, v, __ATOMIC_RELAXED, __HIP_MEMORY_SCOPE_AGENT);
}
__device__ __forceinline__ u64 ld_h64(const u64* p) {
  return __hip_atomic_load(p, __ATOMIC_RELAXED, __HIP_MEMORY_SCOPE_AGENT);
}
__device__ __forceinline__ void st_h64(u64* p, u64 v) {
  __hip_atomic_store(p, v, __ATOMIC_RELAXED, __HIP_MEMORY_SCOPE_AGENT);
}

template <int CTRL>
__device__ __forceinline__ float dppadd(float x) {
  int s = __builtin_amdgcn_update_dpp(0, __float_as_int(x), CTRL, 0xf, 0xf, true);
  return x + __int_as_float(s);
}
__device__ __forceinline__ float red16(float v) {
  v = dppadd<0xB1>(v);   // ^1
  v = dppadd<0x4E>(v);   // ^2
  v = dppadd<0x141>(v);  // ^7 (row_half_mirror)
  v = dppadd<0x140>(v);  // ^15 (row_mirror)
  return v;
}

// 256 WGs x 512 thr, 1 WG/CU. Group g=bid&7: batches [8g,8g+8); WG j=bid>>3:
// units [8j,8j+8) of both layers, weights in VGPRs. R3's proven A/B half
// lockstep (publish early / poll late => ~1 half-phase slack on flag AND
// data), with: DPP in-register k-reduce (no partial-LDS roundtrip), single
// gat->wave1 coalesced 128B publish (full-line sc1 stores, no write amp),
// wave0-only poll, lgkm-only B3 so prefetches ride across phases.
__global__ __launch_bounds__(512, 1) void lstm_persistent(
    const float* __restrict__ x,
    const float* __restrict__ wih0, const float* __restrict__ whh0,
    const float* __restrict__ bih0, const float* __restrict__ bhh0,
    const float* __restrict__ wih1, const float* __restrict__ whh1,
    const float* __restrict__ bih1, const float* __restrict__ bhh1,
    const float* __restrict__ fcw, const float* __restrict__ fcb,
    float* __restrict__ out,
    float* __restrict__ h0buf, float* __restrict__ h1buf,
    int* __restrict__ flags)
{
  extern __shared__ float sm[];
  float* zz  = sm;             // [4][ZROW] = [x|h0(it-1)|h1(it-2)] per half-batch
  float* gat = sm + 4 * ZROW;  // [2][4][8] = [layer][b_loc][u]

  const int tid = threadIdx.x;
  const int bid = blockIdx.x;
  const int g = bid & 7;
  const int j = bid >> 3;
  const int b0 = g * BPG;
  int* fA = flags + g * 32;
  int* fB = flags + 256 + g * 32;

  const int wave = tid >> 6, lane = tid & 63;
  const bool isL0 = (wave < 4);
  const int ks = lane & 15;         // k-slice
  const int u2 = (lane >> 4) & 1;   // unit-in-wave
  const int bg = lane >> 5;         // batch-pair
  const int u = (wave & 3) * 2 + u2;
  const int col = j * 8 + u;
  const int sel = ks & 1;           // act-dedup batch select
  const int myb = bg * 2 + sel;

  // ---- weights + bias into registers (k = ks*4 + 64*c + e) ----
  float w[4][32];
  float bs[4];
  if (isL0) {
#pragma unroll
    for (int gt = 0; gt < 4; ++gt) {
      const int R = gt * NH + col;
      bs[gt] = bih0[R] + bhh0[R];
#pragma unroll
      for (int c = 0; c < 6; ++c)
#pragma unroll
        for (int e = 0; e < 4; ++e) {
          const int k = ks * 4 + 64 * c + e;
          w[gt][c * 4 + e] = (k < NI) ? wih0[R * NI + k] : whh0[R * NH + (k - NI)];
        }
#pragma unroll
      for (int q = 24; q < 32; ++q) w[gt][q] = 0.0f;
    }
  } else {
#pragma unroll
    for (int gt = 0; gt < 4; ++gt) {
      const int R = gt * NH + col;
      bs[gt] = bih1[R] + bhh1[R];
#pragma unroll
      for (int c = 0; c < 8; ++c)
#pragma unroll
        for (int e = 0; e < 4; ++e) {
          const int k = ks * 4 + 64 * c + e;
          w[gt][c * 4 + e] = (k < NH) ? wih1[R * NH + k] : whh1[R * NH + (k - NH)];
        }
    }
  }

  // ---- stage/prefetch role: thread -> (src-WG pj, local batch pb, u-pair pu)
  const int pj = tid >> 4;        // 0..31
  const int pb = (tid >> 2) & 3;  // 0..3
  const int pu = tid & 3;         // 0..3
  const int stage_h0 = pb * ZROW + 128 + pj * 8 + pu * 2;
  const int stage_h1 = pb * ZROW + 384 + pj * 8 + pu * 2;
  const int pre_base = g * 2048 + pj * 64 + pu * 2;  // + (oxb+pb)*8 + par*16384

  // x duty: tids 128..255 (waves 2-3), 16B each
  const bool xw = (tid >= 128 && tid < 256);
  const int xt = tid - 128;
  const int xbb = xt >> 5, xi4 = (xt & 31) * 4;
  const float* xA = x + (size_t)(b0 + 0 + xbb) * NT * NI + xi4;
  const float* xB = x + (size_t)(b0 + 4 + xbb) * NT * NI + xi4;

  float cA = 0.f, cB = 0.f;  // cell for (u, myb) per half
  u64 rh0 = 0, rh1 = 0;
  float4 xv = make_float4(0.f, 0.f, 0.f, 0.f);
  if (xw) xv = *reinterpret_cast<const float4*>(xA);  // x(0), half A
  __syncthreads();

#pragma unroll 1
  for (int it = 0; it <= NT; ++it) {
#pragma unroll
    for (int half = 0; half < 2; ++half) {
      const int xb = half ? 4 : 0;
      const int oxb = half ? 0 : 4;
      const int nit = half ? it + 1 : it;  // prefetch-target iteration
      int* fSelf = half ? fB : fA;
      int* fOther = half ? fA : fB;

      // ---- S1: stage regs -> LDS ----
      if (xw && it < NT)
        *reinterpret_cast<float4*>(&zz[xbb * ZROW + xi4]) = xv;
      *reinterpret_cast<u64*>(&zz[stage_h0]) = rh0;
      *reinterpret_cast<u64*>(&zz[stage_h1]) = rh1;
      __syncthreads();  // B1

      // ---- dot (L0(it) on waves 0-3, L1(it-1) on waves 4-7) ----
      const bool have = isL0 ? (it < NT) : (it >= 1);
      float acc[4][2] = {{0.f, 0.f}, {0.f, 0.f}, {0.f, 0.f}, {0.f, 0.f}};
      if (have) {
        const int koff = isL0 ? (ks * 4) : (128 + ks * 4);
        const float* z0 = &zz[(bg * 2 + 0) * ZROW + koff];
        const float* z1 = &zz[(bg * 2 + 1) * ZROW + koff];
        const int NC = isL0 ? 6 : 8;
#pragma unroll
        for (int c = 0; c < 8; ++c) {
          if (c < NC) {
            const float4 v0 = *reinterpret_cast<const float4*>(z0 + 64 * c);
            const float4 v1 = *reinterpret_cast<const float4*>(z1 + 64 * c);
#pragma unroll
            for (int gt = 0; gt < 4; ++gt) {
              acc[gt][0] = fmaf(w[gt][c * 4 + 0], v0.x, acc[gt][0]);
              acc[gt][0] = fmaf(w[gt][c * 4 + 1], v0.y, acc[gt][0]);
              acc[gt][0] = fmaf(w[gt][c * 4 + 2], v0.z, acc[gt][0]);
              acc[gt][0] = fmaf(w[gt][c * 4 + 3], v0.w, acc[gt][0]);
              acc[gt][1] = fmaf(w[gt][c * 4 + 0], v1.x, acc[gt][1]);
              acc[gt][1] = fmaf(w[gt][c * 4 + 1], v1.y, acc[gt][1]);
              acc[gt][1] = fmaf(w[gt][c * 4 + 2], v1.z, acc[gt][1]);
              acc[gt][1] = fmaf(w[gt][c * 4 + 3], v1.w, acc[gt][1]);
            }
          }
        }
      }

      // ---- wave0 poll (post-dot: ~1 half-phase of producer slack) ----
      if (wave == 0 && nit >= 1 && nit <= NT) {
        int guard = 0;
        for (;;) {
          const int v = (lane < 32) ? ld_flag(&fOther[lane]) : 0x7fffffff;
          if (__all(v >= nit)) break;
          __builtin_amdgcn_s_sleep(1);
          if (++guard > 50000000) break;
        }
      }
      __syncthreads();  // B2 (releases prefetch)

      // ---- prefetch next half's h0(nit-1), h1(nit-2), x(nit) ----
      if (nit <= NT) {
        const int fp0 = (nit - 1) & 1;  // h0(nit-1) slot
        const int fp1 = nit & 1;        // h1(nit-2) slot
        const int off = (oxb + pb) * 8 + pre_base;
        rh0 = ld_h64(reinterpret_cast<const u64*>(h0buf + fp0 * 16384 + off));
        rh1 = ld_h64(reinterpret_cast<const u64*>(h1buf + fp1 * 16384 + off));
        if (xw && nit < NT)
          xv = *reinterpret_cast<const float4*>((half ? xA : xB) +
                                                (size_t)nit * NI);
      }

      // ---- red16 + act + gat (covers prefetch latency) ----
      if (have) {
        float sg[4];
#pragma unroll
        for (int gt = 0; gt < 4; ++gt) {
          const float ra = red16(acc[gt][0]);
          const float rb = red16(acc[gt][1]);
          sg[gt] = (sel ? rb : ra) + bs[gt];
        }
        float c = half ? cB : cA;
        const float h = lstm_act(sg[0], sg[1], sg[2], sg[3], c);
        if (half) cB = c; else cA = c;
        if (ks < 2) gat[(isL0 ? 0 : 32) + myb * 8 + u] = h;
      }
      asm volatile("s_waitcnt lgkmcnt(0)" ::: "memory");
      __builtin_amdgcn_s_barrier();  // B3 (lgkm-only: prefetches ride across)

      // ---- wave1: coalesced 128B/layer publish, drain own, flag ----
      if (wave == 1) {
        if (lane < 32) {
          const int L = lane >> 4, idx = lane & 15;
          const bool ok = L ? (it >= 1) : (it < NT);
          if (ok) {
            const int par = L ? ((it - 1) & 1) : (it & 1);
            float* hb = L ? h1buf : h0buf;
            const u64 v = *reinterpret_cast<const u64*>(&gat[L * 32 + idx * 2]);
            st_h64(reinterpret_cast<u64*>(hb + par * 16384 + g * 2048 + j * 64 +
                                          xb * 8 + idx * 2),
                   v);
          }
        }
        asm volatile("s_waitcnt vmcnt(0)" ::: "memory");
        if (lane == 0) st_flag(&fSelf[j], it + 1);
      }
    }
  }

  // ---- epilogue: FC over relu(h1[NT-1]) by WG j==0 of each group ----
  if (j == 0) {
    if (tid < 32) {
      int guard = 0;
      while (ld_flag(&fA[tid]) < NT + 1 || ld_flag(&fB[tid]) < NT + 1) {
        __builtin_amdgcn_s_sleep(1);
        if (++guard > 50000000) break;
      }
    }
    __syncthreads();
    const int bb = tid >> 6, ln = tid & 63;  // 8 waves = 8 batches
    // h1(NT-1): parity 1; cols ln*4..ln*4+3 -> (jj=ln>>1, uo=(ln&1)*4)
    const float* src = h1buf + 16384 + g * 2048 + (ln >> 1) * 64 + bb * 8 +
                       (ln & 1) * 4;
    const u64 u0 = ld_h64(reinterpret_cast<const u64*>(src));
    const u64 u1 = ld_h64(reinterpret_cast<const u64*>(src + 2));
    const float ha = __uint_as_float((unsigned)u0);
    const float hb = __uint_as_float((unsigned)(u0 >> 32));
    const float hc = __uint_as_float((unsigned)u1);
    const float hd = __uint_as_float((unsigned)(u1 >> 32));
    const float4 w4 = *reinterpret_cast<const float4*>(fcw + ln * 4);
    float pr = fmaxf(ha, 0.f) * w4.x + fmaxf(hb, 0.f) * w4.y +
               fmaxf(hc, 0.f) * w4.z + fmaxf(hd, 0.f) * w4.w;
#pragma unroll
    for (int off = 32; off >= 1; off >>= 1) pr += __shfl_down(pr, off, 64);
    if (ln == 0) out[b0 + bb] = pr + fcb[0];
  }
}

extern "C" void kernel_launch(void* const* d_in, const int* in_sizes, int n_in,
                              void* d_out, int out_size, void* d_ws, size_t ws_size,
                              hipStream_t stream) {
  (void)in_sizes; (void)n_in; (void)out_size; (void)ws_size;
  const float* x    = (const float*)d_in[0];
  const float* wih0 = (const float*)d_in[1];
  const float* whh0 = (const float*)d_in[2];
  const float* bih0 = (const float*)d_in[3];
  const float* bhh0 = (const float*)d_in[4];
  const float* wih1 = (const float*)d_in[5];
  const float* whh1 = (const float*)d_in[6];
  const float* bih1 = (const float*)d_in[7];
  const float* bhh1 = (const float*)d_in[8];
  const float* fcw  = (const float*)d_in[9];
  const float* fcb  = (const float*)d_in[10];
  float* out = (float*)d_out;

  float* ws = (float*)d_ws;
  float* h0buf = ws;                     // [2][8 g][32 j][8 b][8 u] = 32768 f32
  float* h1buf = ws + 32768;             // [2][8][32][8][8]
  int* flags = (int*)(ws + 65536);       // [2][8][32]

  const size_t zbytes = (size_t)65536 * sizeof(float) + 512 * sizeof(int);
  hipMemsetAsync(d_ws, 0, zbytes, stream);

  size_t shmem = 96 * 1024;  // force 1 WG/CU (co-residency, CU exclusivity)
  if (hipFuncSetAttribute(reinterpret_cast<const void*>(lstm_persistent),
                          hipFuncAttributeMaxDynamicSharedMemorySize,
                          (int)shmem) != hipSuccess) {
    shmem = (4 * ZROW + 64 + 16) * sizeof(float);  // real footprint fallback
  }

  hipLaunchKernelGGL(lstm_persistent, dim3(256), dim3(512), shmem, stream,
                     x, wih0, whh0, bih0, bhh0, wih1, whh1, bih1, bhh1,
                     fcw, fcb, out, h0buf, h1buf, flags);
}

// Round 10
// 23124.521 us; speedup vs baseline: 1.4616x; 1.4616x over previous
//
#include <hip/hip_runtime.h>

#define NT 2048
#define NI 128
#define NH 256
#define BPG 8
#define XS_ROW 132
#define HS_ROW 260

typedef unsigned long long u64;

__device__ __forceinline__ float sigm(float v) {
  return 1.0f / (1.0f + __expf(-v));
}
__device__ __forceinline__ float tanh_fast(float v) {
  v = fminf(fmaxf(v, -15.0f), 15.0f);
  float e = __expf(-2.0f * v);
  return (1.0f - e) / (1.0f + e);
}
__device__ __forceinline__ float lstm_act(float gi, float gf, float gg, float go,
                                          float& c) {
  const float ii = sigm(gi), ff = sigm(gf), gt = tanh_fast(gg), oo = sigm(go);
  c = ff * c + ii * gt;
  return oo * tanh_fast(c);
}

// relaxed agent-scope: cross-XCD coherent, no cache-maintenance ops
__device__ __forceinline__ int ld_flag(const int* p) {
  return __hip_atomic_load(p, __ATOMIC_RELAXED, __HIP_MEMORY_SCOPE_AGENT);
}
__device__ __forceinline__ void st_flag(int* p, int v) {
  __hip_atomic_store(p, v, __ATOMIC_RELAXED, __HIP_MEMORY_SCOPE_AGENT);
}
__device__ __forceinline__ void st_h32(float* p, float v) {
  __hip_atomic_store(p, v, __ATOMIC_RELAXED, __HIP_MEMORY_SCOPE_AGENT);
}
__device__ __forceinline__ u64 ld_h64(const u64* p) {
  return __hip_atomic_load(p, __ATOMIC_RELAXED, __HIP_MEMORY_SCOPE_AGENT);
}

template <int CTRL>
__device__ __forceinline__ float dppadd(float x) {
  int s = __builtin_amdgcn_update_dpp(0, __float_as_int(x), CTRL, 0xf, 0xf, true);
  return x + __int_as_float(s);
}
__device__ __forceinline__ float red16(float v) {
  v = dppadd<0xB1>(v);   // ^1
  v = dppadd<0x4E>(v);   // ^2
  v = dppadd<0x141>(v);  // ^7 (row_half_mirror)
  v = dppadd<0x140>(v);  // ^15 (row_mirror)
  return v;
}

// one 64-wide k-chunk: 4 batch-rows x 4 gates (16 FMA per row)
__device__ __forceinline__ void chunk4(float acc[4][4], const float* row0,
                                       int rst, const float* wr, int wc) {
#pragma unroll
  for (int b = 0; b < 4; ++b) {
    const float4 v = *reinterpret_cast<const float4*>(row0 + b * rst);
#pragma unroll
    for (int gt = 0; gt < 4; ++gt) {
      acc[gt][b] = fmaf(wr[gt * 32 + wc + 0], v.x, acc[gt][b]);
      acc[gt][b] = fmaf(wr[gt * 32 + wc + 1], v.y, acc[gt][b]);
      acc[gt][b] = fmaf(wr[gt * 32 + wc + 2], v.z, acc[gt][b]);
      acc[gt][b] = fmaf(wr[gt * 32 + wc + 3], v.w, acc[gt][b]);
    }
  }
}

// 256 WGs x 512 thr, 1 WG/CU. Group g=bid&7: batches [8g,8g+8); WG j=bid>>3:
// units [8j,8j+8) of both layers, weights in VGPRs. ONE phase per step
// (2050 phases): phase p = L1(p-2) on waves 0-3, L0(p) on waves 4-7.
// Old data (>=1 phase slack): x(p), h0(p-2) -> seg1. Fresh pair
// {h0(p-1), h1(p-3)}: poll AFTER seg1 -> load (4 u64/thread, R7's verified
// mapping) -> land -> B3 -> seg2. Publish = compute threads' 4B stores into
// per-WG-contiguous [g][j][b][u] block; vmcnt(0) -> B4 -> tid0 flag.
__global__ __launch_bounds__(512, 1) void lstm_persistent(
    const float* __restrict__ x,
    const float* __restrict__ wih0, const float* __restrict__ whh0,
    const float* __restrict__ bih0, const float* __restrict__ bhh0,
    const float* __restrict__ wih1, const float* __restrict__ whh1,
    const float* __restrict__ bih1, const float* __restrict__ bhh1,
    const float* __restrict__ fcw, const float* __restrict__ fcb,
    float* __restrict__ out,
    float* __restrict__ h0buf, float* __restrict__ h1buf,
    int* __restrict__ flags)
{
  extern __shared__ float sm[];
  float* xs  = sm;                       // [2][8][XS_ROW]  x(p) at slot p&1
  float* h0s = sm + 2 * 8 * XS_ROW;      // [2][8][HS_ROW]  land slot (p-1)&1
  float* h1s = h0s + 2 * 8 * HS_ROW;     // [8][HS_ROW]     h1(p-3)

  const int tid = threadIdx.x;
  const int bid = blockIdx.x;
  const int g = bid & 7;
  const int j = bid >> 3;
  const int b0 = g * BPG;
  int* fl = flags + g * 32;

  const int wave = tid >> 6, lane = tid & 63;
  const bool isL1 = (wave < 4);          // poller wave0 gets the 4-chunk seg1
  const int ks = lane & 15;
  const int u2 = (lane >> 4) & 1;
  const int bg = lane >> 5;
  const int u = (wave & 3) * 2 + u2;
  const int col = j * 8 + u;
  const int bb = ks & 3;                 // this lane's batch-in-quad
  const int myb = bg * 4 + bb;           // local batch 0..7

  // ---- weights + bias (k = ks*4 + 64*c + e, chunk order = seg order) ----
  float w[4][32];
  float bs[4];
  if (isL1) {
#pragma unroll
    for (int gt = 0; gt < 4; ++gt) {
      const int R = gt * NH + col;
      bs[gt] = bih1[R] + bhh1[R];
#pragma unroll
      for (int c = 0; c < 4; ++c)        // seg1: h0(p-2)
#pragma unroll
        for (int e = 0; e < 4; ++e)
          w[gt][c * 4 + e] = wih1[R * NH + ks * 4 + 64 * c + e];
#pragma unroll
      for (int c = 4; c < 8; ++c)        // seg2: h1(p-3)
#pragma unroll
        for (int e = 0; e < 4; ++e)
          w[gt][c * 4 + e] = whh1[R * NH + ks * 4 + 64 * (c - 4) + e];
    }
  } else {
#pragma unroll
    for (int gt = 0; gt < 4; ++gt) {
      const int R = gt * NH + col;
      bs[gt] = bih0[R] + bhh0[R];
#pragma unroll
      for (int c = 0; c < 2; ++c)        // seg1: x(p)
#pragma unroll
        for (int e = 0; e < 4; ++e)
          w[gt][c * 4 + e] = wih0[R * NI + ks * 4 + 64 * c + e];
#pragma unroll
      for (int c = 2; c < 6; ++c)        // seg2: h0(p-1)
#pragma unroll
        for (int e = 0; e < 4; ++e)
          w[gt][c * 4 + e] = whh0[R * NH + ks * 4 + 64 * (c - 2) + e];
#pragma unroll
      for (int q = 24; q < 32; ++q) w[gt][q] = 0.0f;
    }
  }
  const float* wr = &w[0][0];

  // ---- fresh-load/land duty (R7's verified mapping): thread lt handles
  //      8 contiguous floats (4 u64) at group offset lt*8 ->
  //      LDS row (lt&7), col base (lt>>3)*8 ----
  const int lt = tid & 255;
  const int gsrc = g * 2048 + lt * 8;              // float offset in hbuf block
  const int ldst = (lt & 7) * HS_ROW + (lt >> 3) * 8;

  // x duty (tid<256): batch lt>>5, 16B
  const int xb = lt >> 5, xi = (lt & 31) * 4;
  const float* xp = x + (size_t)(b0 + xb) * NT * NI + xi;

  float cell = 0.0f;  // (u, myb) of this thread's layer (4x lane-redundant)
  float4 xv = make_float4(0.f, 0.f, 0.f, 0.f);

  // ---- prologue: stage x(0), preload x(1) ----
  if (tid < 256) {
    const float4 a = *reinterpret_cast<const float4*>(xp);
    *reinterpret_cast<float4*>(&xs[xb * XS_ROW + xi]) = a;
    xv = *reinterpret_cast<const float4*>(xp + NI);
  }
  __syncthreads();

#pragma unroll 1
  for (int p = 0; p <= NT + 1; ++p) {
    const int ps = p & 1, fs = ps ^ 1;
    const float* xcur = xs + ps * (8 * XS_ROW);
    const float* h0old = h0s + ps * (8 * HS_ROW);  // h0(p-2)
    float* h0fr = h0s + fs * (8 * HS_ROW);         // h0(p-1) lands here
    const bool actL1 = isL1 && (p >= 2);           // L1(p-2), p-2 in [0,NT-1]
    const bool actL0 = !isL1 && (p < NT);          // L0(p)

    float acc[4][4];
#pragma unroll
    for (int a0 = 0; a0 < 4; ++a0)
#pragma unroll
      for (int a1 = 0; a1 < 4; ++a1) acc[a0][a1] = 0.0f;

    // ---- seg1 (old data) ----
    if (isL1) {
      if (actL1) {
        const float* r0 = h0old + bg * 4 * HS_ROW + ks * 4;
#pragma unroll
        for (int c = 0; c < 4; ++c) chunk4(acc, r0 + 64 * c, HS_ROW, wr, c * 4);
      }
    } else {
      if (actL0) {
        const float* r0 = xcur + bg * 4 * XS_ROW + ks * 4;
#pragma unroll
        for (int c = 0; c < 2; ++c) chunk4(acc, r0 + 64 * c, XS_ROW, wr, c * 4);
      }
    }

    // ---- poll: peers completed phase p-1 (slack = tail + seg1) ----
    if (p >= 1 && tid < 32) {
      int guard = 0;
      while (ld_flag(&fl[tid]) < p) {
        __builtin_amdgcn_s_sleep(1);
        if (++guard > 50000000) break;
      }
    }
    __syncthreads();  // B2

    // ---- fresh loads: h0(p-1) [thr<256], h1(p-3) [thr>=256], 4 u64 each ----
    u64 r0 = 0, r1 = 0, r2 = 0, r3 = 0;
    if (tid < 256) {
      if (p <= NT) {
        const u64* s = reinterpret_cast<const u64*>(h0buf + fs * 16384 + gsrc);
        r0 = ld_h64(s); r1 = ld_h64(s + 1); r2 = ld_h64(s + 2); r3 = ld_h64(s + 3);
      }
    } else {
      const u64* s = reinterpret_cast<const u64*>(h1buf + fs * 16384 + gsrc);
      r0 = ld_h64(s); r1 = ld_h64(s + 1); r2 = ld_h64(s + 2); r3 = ld_h64(s + 3);
    }

    // ---- land + x stage/prefetch ----
    if (tid < 256) {
      if (p <= NT) {
        u64* d = reinterpret_cast<u64*>(&h0fr[ldst]);
        d[0] = r0; d[1] = r1; d[2] = r2; d[3] = r3;
      }
      if (p + 1 <= NT - 1)
        *reinterpret_cast<float4*>(&xs[fs * (8 * XS_ROW) + xb * XS_ROW + xi]) = xv;
      if (p + 2 <= NT - 1)
        xv = *reinterpret_cast<const float4*>(xp + (size_t)(p + 2) * NI);
    } else {
      u64* d = reinterpret_cast<u64*>(&h1s[ldst]);
      d[0] = r0; d[1] = r1; d[2] = r2; d[3] = r3;
    }
    __syncthreads();  // B3

    // ---- seg2 (fresh data) ----
    if (isL1) {
      if (actL1) {
        const float* r = h1s + bg * 4 * HS_ROW + ks * 4;
#pragma unroll
        for (int c = 0; c < 4; ++c)
          chunk4(acc, r + 64 * c, HS_ROW, wr, (c + 4) * 4);
      }
    } else {
      if (actL0) {
        const float* r = h0fr + bg * 4 * HS_ROW + ks * 4;
#pragma unroll
        for (int c = 0; c < 4; ++c)
          chunk4(acc, r + 64 * c, HS_ROW, wr, (c + 2) * 4);
      }
    }

    // ---- red16 + act + publish ----
    if (actL1 || actL0) {
      float sg[4];
#pragma unroll
      for (int gt = 0; gt < 4; ++gt) {
        const float q0 = red16(acc[gt][0]);
        const float q1 = red16(acc[gt][1]);
        const float q2 = red16(acc[gt][2]);
        const float q3 = red16(acc[gt][3]);
        sg[gt] = (bb == 0 ? q0 : bb == 1 ? q1 : bb == 2 ? q2 : q3) + bs[gt];
      }
      const float h = lstm_act(sg[0], sg[1], sg[2], sg[3], cell);
      if (ks < 4) {  // one lane per (u, myb)
        float* hb = isL1 ? h1buf : h0buf;  // L1 -> h1(p-2), slot (p-2)&1 = ps
        st_h32(hb + ps * 16384 + g * 2048 + j * 64 + myb * 8 + u, h);
      }
    }
    asm volatile("s_waitcnt vmcnt(0)" ::: "memory");  // publishes ack'd
    __syncthreads();  // B4
    if (tid == 0) st_flag(&fl[j], p + 1);
  }

  // ---- epilogue: FC over relu(h1[NT-1]) by WG j==0 of each group ----
  if (j == 0) {
    if (tid < 32) {
      int guard = 0;
      while (ld_flag(&fl[tid]) < NT + 2) {
        __builtin_amdgcn_s_sleep(1);
        if (++guard > 50000000) break;
      }
    }
    __syncthreads();
    const int bt = tid >> 6, ln = tid & 63;  // 8 waves = 8 batches
    // h1(NT-1) slot (NT-1)&1 = 1; cols 4*ln..4*ln+3 = (jj=ln>>1, off=(ln&1)*4)
    const float* src = h1buf + 16384 + g * 2048 + (ln >> 1) * 64 + bt * 8 +
                       (ln & 1) * 4;
    const u64 u0 = ld_h64(reinterpret_cast<const u64*>(src));
    const u64 u1 = ld_h64(reinterpret_cast<const u64*>(src + 2));
    const float ha = __uint_as_float((unsigned)u0);
    const float hb = __uint_as_float((unsigned)(u0 >> 32));
    const float hc = __uint_as_float((unsigned)u1);
    const float hd = __uint_as_float((unsigned)(u1 >> 32));
    const float4 w4 = *reinterpret_cast<const float4*>(fcw + ln * 4);
    float pr = fmaxf(ha, 0.f) * w4.x + fmaxf(hb, 0.f) * w4.y +
               fmaxf(hc, 0.f) * w4.z + fmaxf(hd, 0.f) * w4.w;
#pragma unroll
    for (int off = 32; off >= 1; off >>= 1) pr += __shfl_down(pr, off, 64);
    if (ln == 0) out[b0 + bt] = pr + fcb[0];
  }
}

extern "C" void kernel_launch(void* const* d_in, const int* in_sizes, int n_in,
                              void* d_out, int out_size, void* d_ws, size_t ws_size,
                              hipStream_t stream) {
  (void)in_sizes; (void)n_in; (void)out_size; (void)ws_size;
  const float* x    = (const float*)d_in[0];
  const float* wih0 = (const float*)d_in[1];
  const float* whh0 = (const float*)d_in[2];
  const float* bih0 = (const float*)d_in[3];
  const float* bhh0 = (const float*)d_in[4];
  const float* wih1 = (const float*)d_in[5];
  const float* whh1 = (const float*)d_in[6];
  const float* bih1 = (const float*)d_in[7];
  const float* bhh1 = (const float*)d_in[8];
  const float* fcw  = (const float*)d_in[9];
  const float* fcb  = (const float*)d_in[10];
  float* out = (float*)d_out;

  float* ws = (float*)d_ws;
  float* h0buf = ws;                     // [2][8 g][32 j][8 b][8 u] = 32768 f32
  float* h1buf = ws + 32768;             // [2][8][32][8][8]
  int* flags = (int*)(ws + 65536);       // [8][32]

  const size_t zbytes = (size_t)65536 * sizeof(float) + 256 * sizeof(int);
  hipMemsetAsync(d_ws, 0, zbytes, stream);

  size_t shmem = 96 * 1024;  // force 1 WG/CU (co-residency, CU exclusivity)
  if (hipFuncSetAttribute(reinterpret_cast<const void*>(lstm_persistent),
                          hipFuncAttributeMaxDynamicSharedMemorySize,
                          (int)shmem) != hipSuccess) {
    shmem = (2 * 8 * XS_ROW + 2 * 8 * HS_ROW + 8 * HS_ROW + 16) * sizeof(float);
  }

  hipLaunchKernelGGL(lstm_persistent, dim3(256), dim3(512), shmem, stream,
                     x, wih0, whh0, bih0, bhh0, wih1, whh1, bih1, bhh1,
                     fcw, fcb, out, h0buf, h1buf, flags);
}